// Round 14
// baseline (75.604 us; speedup 1.0000x reference)
//
#include <hip/hip_runtime.h>

typedef float f4 __attribute__((ext_vector_type(4)));

#define LL 64
#define BB 2048
#define DD 512
#define GB 2                  // batches per block (tid>>7 selects)
#define NBLK (BB / GB)        // 1024 blocks x 256 threads = 4 waves/SIMD
#define LOG2E 1.442695040888963f

__device__ __forceinline__ float fexp2(float v){ return __builtin_amdgcn_exp2f(v); }
__device__ __forceinline__ float frcp_(float v){ return __builtin_amdgcn_rcpf(v); }
__device__ __forceinline__ float fsigm(float z){ return frcp_(1.0f + fexp2(-LOG2E*z)); }
__device__ __forceinline__ float ftanh_(float z){ return 1.0f - 2.0f*frcp_(1.0f + fexp2(2.0f*LOG2E*z)); }
__device__ __forceinline__ f4 ld4(const float* __restrict__ p){ return *(const f4*)p; }
__device__ __forceinline__ f4 lds_ld4(const float* p){ return *(const f4*)p; }
__device__ __forceinline__ f4 vexp2(f4 v){ f4 r; r[0]=fexp2(v[0]); r[1]=fexp2(v[1]); r[2]=fexp2(v[2]); r[3]=fexp2(v[3]); return r; }
__device__ __forceinline__ f4 vrcp(f4 v){ f4 r; r[0]=frcp_(v[0]); r[1]=frcp_(v[1]); r[2]=frcp_(v[2]); r[3]=frcp_(v[3]); return r; }

// full 16-lane-row reduce: quad butterfly + row_shr:4 + row_shr:8.
// lane%16==15 ends with the sum of its 16-lane row. Pure VALU (DPP).
__device__ __forceinline__ float row16_reduce(float v){
  int t;
  t = __builtin_amdgcn_update_dpp(0, __builtin_bit_cast(int, v), 0xB1,  0xF, 0xF, true);
  v += __builtin_bit_cast(float, t);
  t = __builtin_amdgcn_update_dpp(0, __builtin_bit_cast(int, v), 0x4E,  0xF, 0xF, true);
  v += __builtin_bit_cast(float, t);
  t = __builtin_amdgcn_update_dpp(0, __builtin_bit_cast(int, v), 0x114, 0xF, 0xF, true); // row_shr:4
  v += __builtin_bit_cast(float, t);
  t = __builtin_amdgcn_update_dpp(0, __builtin_bit_cast(int, v), 0x118, 0xF, 0xF, true); // row_shr:8
  v += __builtin_bit_cast(float, t);
  return v;
}

// async global->LDS, 16B per lane: LDS dst = uniform base + lane*16
__device__ __forceinline__ void stage16(const float* g, float* l){
  __builtin_amdgcn_global_load_lds(
      (const __attribute__((address_space(1))) void*)g,
      (__attribute__((address_space(3))) void*)l, 16, 0, 0);
}

__global__ __launch_bounds__(256, 4) void rnn_fused_kernel(
    const float* __restrict__ x,
    const float* __restrict__ wxp, const float* __restrict__ wgp,
    const float* __restrict__ whp, const float* __restrict__ wup,
    const float* __restrict__ mp,  const float* __restrict__ fcw,
    const float* __restrict__ fcb, float* __restrict__ out)
{
  __align__(16) __shared__ float wbuf[3][5][DD];  // 30 KB: 3-deep weight-plane ring
  __shared__ float part[GB][LL][9];               // 4.6 KB partials (8 groups + pad)

  const int tid  = threadIdx.x;
  const int b0   = blockIdx.x;
  const int lane = tid & 63;
  const int wv   = __builtin_amdgcn_readfirstlane(tid >> 6);   // wave id 0..3
  const int g    = tid >> 7;            // batch half
  const int dt   = tid & 127;           // d-slice 0..127
  const int d0   = dt << 2;
  const int pgrp = dt >> 4;             // 0..7

  const f4 fw = ld4(fcw + d0);
  const size_t PL = (size_t)BB * DD;
  const float* xbase = x + (size_t)(b0 * GB + g) * DD + d0;

  // uniform select over the 5 kernel-arg pointers (cselect chain, no arrays)
  auto wptr = [&](int a) -> const float* {
    return (a == 0) ? wxp : (a == 1) ? wgp : (a == 2) ? whp : (a == 3) ? wup : mp;
  };
  // 10 chunks of 1KB per plane (5 arrays x 2 halves); wave w stages 3 chunks
  // (waves 2,3 re-stage chunks 0,1 -> uniform 3 stages/wave, identical data)
  const int ck0 = wv, ck1 = wv + 4, ck2 = (wv + 8) % 10;

  auto STAGE = [&](int s){
    const int bi = s % 3;
    float* lb = &wbuf[bi][0][0];
    #pragma unroll
    for (int i = 0; i < 3; ++i){
      const int c  = (i == 0) ? ck0 : (i == 1) ? ck1 : ck2;
      const int a  = c >> 1, hh = c & 1;
      stage16(wptr(a) + (size_t)s * DD + hh * 256 + lane * 4,
              lb + a * DD + hh * 256);
    }
  };

  // ---- t = 0 (plane 0 needs only wx, wg; plain loads)
  f4 h0v, h, xb;
  {
    f4 x0  = ld4(xbase);
    f4 w0x = ld4(wxp + d0);
    f4 w0g = ld4(wgp + d0);
    float c0 = row16_reduce(x0[0]*fw[0] + x0[1]*fw[1] + x0[2]*fw[2] + x0[3]*fw[3]);
    if ((tid & 15) == 15) part[g][0][pgrp] = c0;
    float c1 = 0.0f;
    #pragma unroll
    for (int j = 0; j < 4; ++j){
      h0v[j] = ftanh_(x0[j] * w0x[j]);
      xb[j]  = h0v[j] * w0g[j] + x0[j];
      c1    += xb[j] * fw[j];
    }
    h = h0v;
    c1 = row16_reduce(c1);
    if ((tid & 15) == 15) part[g][1][pgrp] = c1;
  }

  // ---- prologue: stage weight planes 1,2; prime 3-deep x register ring
  asm volatile("" ::: "memory");
  STAGE(1); STAGE(2);
  asm volatile("" ::: "memory");
  f4 xq0 = ld4(xbase + 1 * PL);
  f4 xq1 = ld4(xbase + 2 * PL);
  f4 xq2 = ld4(xbase + 3 * PL);
  asm volatile("s_waitcnt vmcnt(3)" ::: "memory");  // stages done; x-ring in flight
  __syncthreads();

  // ---- main scan t = 1..62: read plane t from wbuf[t%3] (staged 2 iters ago),
  //      stage plane t+2, load x plane t+3. Counted vmcnt(4) = this iter's
  //      3 stages + 1 x-load stay in flight; everything older (incl. the
  //      stage of plane t+1) is forced complete before the barrier.
  #pragma unroll 2
  for (int t = 1; t < LL - 1; ++t){
    const int sp = (t + 2 < LL - 1) ? (t + 2) : (LL - 2);
    const int xp = (t + 3 < LL - 1) ? (t + 3) : (LL - 2);
    STAGE(sp);
    f4 xN = ld4(xbase + (size_t)xp * PL);

    const int bi = t % 3;
    const float* wb = &wbuf[bi][0][0];
    f4 wxc = lds_ld4(wb + 0 * DD + d0);
    f4 wgc = lds_ld4(wb + 1 * DD + d0);
    f4 whc = lds_ld4(wb + 2 * DD + d0);
    f4 wuc = lds_ld4(wb + 3 * DD + d0);
    f4 mmc = lds_ld4(wb + 4 * DD + d0);

    f4 wxs = wxc * (2.0f * LOG2E);
    f4 whs = whc * (-LOG2E);
    f4 wus = wuc * (-LOG2E);

    f4 xtr  = xb + mmc * (xq0 - xb);
    f4 u    = 1.0f - 2.0f * vrcp(1.0f + vexp2(xtr * wxs));
    f4 sarg = h * whs + u * wus;
    f4 ff   = vrcp(1.0f + vexp2(sarg)) * mmc;
    f4 mn   = __builtin_elementwise_min(1.0f - ff, u);
    f4 hn   = __builtin_elementwise_max(ff * h + mn, h0v);
    h  = hn;
    xb = hn * wgc + xtr;

    float cc = row16_reduce(xb[0]*fw[0] + xb[1]*fw[1] + xb[2]*fw[2] + xb[3]*fw[3]);
    if ((tid & 15) == 15) part[g][t + 1][pgrp] = cc;

    xq0 = xq1; xq1 = xq2; xq2 = xN;

    asm volatile("s_waitcnt vmcnt(4)" ::: "memory");
    __syncthreads();
  }

  // ---- epilogue (loop ended with a barrier): 128 threads = 2 g x 64 l
  if (tid < GB * LL){
    const int l  = tid & 63;
    const int g2 = tid >> 6;
    float s = 0.0f;
    #pragma unroll
    for (int j = 0; j < 8; ++j) s += part[g2][l][j];
    out[(size_t)l * BB + (b0 * GB + g2)] = fsigm(s + fcb[0]);
  }
}

extern "C" void kernel_launch(void* const* d_in, const int* in_sizes, int n_in,
                              void* d_out, int out_size, void* d_ws, size_t ws_size,
                              hipStream_t stream)
{
  const float* x   = (const float*)d_in[0];
  const float* wx  = (const float*)d_in[1];
  const float* wg  = (const float*)d_in[2];
  const float* wh  = (const float*)d_in[3];
  const float* wu  = (const float*)d_in[4];
  const float* m   = (const float*)d_in[5];
  const float* fcw = (const float*)d_in[6];
  const float* fcb = (const float*)d_in[7];
  float* out = (float*)d_out;
  rnn_fused_kernel<<<dim3(NBLK), dim3(256), 0, stream>>>(x, wx, wg, wh, wu, m, fcw, fcb, out);
}

// Round 15
// 64.672 us; speedup vs baseline: 1.1690x; 1.1690x over previous
//
#include <hip/hip_runtime.h>

typedef float f2 __attribute__((ext_vector_type(2)));

#define LL 64
#define BB 2048
#define DD 512
#define GB 2                 // batches per block (consecutive)
#define NBLK (BB / GB)       // 1024 blocks
#define NT 256               // 4 waves/block -> 16 waves/CU if VGPR<=128
#define DEPTH 4              // prefetch depth for x AND weights
#define LOG2E 1.442695040888963f

__device__ __forceinline__ float fexp2(float v){ return __builtin_amdgcn_exp2f(v); }
__device__ __forceinline__ float frcp_(float v){ return __builtin_amdgcn_rcpf(v); }
__device__ __forceinline__ float fsigm(float z){ return frcp_(1.0f + fexp2(-LOG2E*z)); }
__device__ __forceinline__ float ftanh_(float z){ return 1.0f - 2.0f*frcp_(1.0f + fexp2(2.0f*LOG2E*z)); }

__device__ __forceinline__ f2 ld2(const float* __restrict__ p){ return *(const f2*)p; }
__device__ __forceinline__ f2 vexp2(f2 v){ f2 r; r[0]=fexp2(v[0]); r[1]=fexp2(v[1]); return r; }
__device__ __forceinline__ f2 vrcp(f2 v){ f2 r; r[0]=frcp_(v[0]); r[1]=frcp_(v[1]); return r; }

// 16-lane-row reduce, pure-VALU DPP (validated R14): lane%16==15 holds row sum
__device__ __forceinline__ float row16_reduce(float v){
  int t;
  t = __builtin_amdgcn_update_dpp(0, __builtin_bit_cast(int, v), 0xB1,  0xF, 0xF, true);
  v += __builtin_bit_cast(float, t);
  t = __builtin_amdgcn_update_dpp(0, __builtin_bit_cast(int, v), 0x4E,  0xF, 0xF, true);
  v += __builtin_bit_cast(float, t);
  t = __builtin_amdgcn_update_dpp(0, __builtin_bit_cast(int, v), 0x114, 0xF, 0xF, true); // row_shr:4
  v += __builtin_bit_cast(float, t);
  t = __builtin_amdgcn_update_dpp(0, __builtin_bit_cast(int, v), 0x118, 0xF, 0xF, true); // row_shr:8
  v += __builtin_bit_cast(float, t);
  return v;
}

// (256,1): block size only — NO VGPR cap (R10/R13 lesson). Target natural ~115.
__global__ __launch_bounds__(NT, 1) void rnn_fused_kernel(
    const float* __restrict__ x,
    const float* __restrict__ wxp, const float* __restrict__ wgp,
    const float* __restrict__ whp, const float* __restrict__ wup,
    const float* __restrict__ mp,  const float* __restrict__ fcw,
    const float* __restrict__ fcb, float* __restrict__ out)
{
  __shared__ float part[GB][LL][17];   // [g][l][16 row-groups + pad] = 8.7KB
  const int tid  = threadIdx.x;
  const int b0   = blockIdx.x;
  const int d0   = tid << 1;           // 2 d's per thread, 256 threads cover 512
  const int pgrp = tid >> 4;           // 16-thread row-groups: 0..15

  const f2 fw = ld2(fcw + d0);
  const size_t PL = (size_t)BB * DD;

  // consecutive batches; each thread processes BOTH batches at its d-slice
  const float* xbase[GB];
  #pragma unroll
  for (int g = 0; g < GB; ++g)
    xbase[g] = x + (size_t)(b0 * GB + g) * DD + d0;

  // ---- deep prefetch rings: x[1..DEPTH] per g, weights[1..DEPTH]
  f2 xq[GB][DEPTH];
  f2 wxq[DEPTH], wgq[DEPTH], whq[DEPTH], wuq[DEPTH], mmq[DEPTH];
  #pragma unroll
  for (int k = 0; k < DEPTH; ++k){
    const int s = 1 + k;
    #pragma unroll
    for (int g = 0; g < GB; ++g)
      xq[g][k] = ld2(xbase[g] + (size_t)s * PL);
    wxq[k] = ld2(wxp + s * DD + d0);
    wgq[k] = ld2(wgp + s * DD + d0);
    whq[k] = ld2(whp + s * DD + d0);
    wuq[k] = ld2(wup + s * DD + d0);
    mmq[k] = ld2(mp  + s * DD + d0);
  }

  // ---- t = 0
  f2 w0x = ld2(wxp + d0);
  f2 w0g = ld2(wgp + d0);
  f2 h0v[GB], h[GB], xb[GB];
  #pragma unroll
  for (int g = 0; g < GB; ++g){
    f2 x0 = ld2(xbase[g]);
    float c0 = row16_reduce(x0[0]*fw[0] + x0[1]*fw[1]);
    if ((tid & 15) == 15) part[g][0][pgrp] = c0;

    float c1 = 0.0f;
    #pragma unroll
    for (int j = 0; j < 2; ++j){
      h0v[g][j] = ftanh_(x0[j] * w0x[j]);
      xb[g][j]  = h0v[g][j] * w0g[j] + x0[j];
      c1       += xb[g][j] * fw[j];
    }
    h[g] = h0v[g];
    c1 = row16_reduce(c1);
    if ((tid & 15) == 15) part[g][1][pgrp] = c1;
  }

  // ---- main scan: t = 1..62; unroll 4 -> ring rotation = register renaming
  #pragma unroll 4
  for (int t = 1; t < LL - 1; ++t){
    const int tpn = (t + DEPTH <= LL - 2) ? (t + DEPTH) : (LL - 2);
    f2 xC[GB];
    #pragma unroll
    for (int g = 0; g < GB; ++g)
      xC[g] = ld2(xbase[g] + (size_t)tpn * PL);
    f2 wxn = ld2(wxp + tpn * DD + d0);
    f2 wgn = ld2(wgp + tpn * DD + d0);
    f2 whn = ld2(whp + tpn * DD + d0);
    f2 wun = ld2(wup + tpn * DD + d0);
    f2 mmn = ld2(mp  + tpn * DD + d0);

    // consume ring fronts (loaded DEPTH iters ago)
    f2 wxs = wxq[0] * (2.0f * LOG2E);
    f2 whs = whq[0] * (-LOG2E);
    f2 wus = wuq[0] * (-LOG2E);
    f2 wgc = wgq[0];
    f2 mmc = mmq[0];

    #pragma unroll
    for (int g = 0; g < GB; ++g){
      f2 xtr  = xb[g] + mmc * (xq[g][0] - xb[g]);
      f2 u    = 1.0f - 2.0f * vrcp(1.0f + vexp2(xtr * wxs));
      f2 sarg = h[g] * whs + u * wus;
      f2 ff   = vrcp(1.0f + vexp2(sarg)) * mmc;
      f2 mn   = __builtin_elementwise_min(1.0f - ff, u);
      f2 hn   = ff * h[g] + mn;
      hn      = __builtin_elementwise_max(hn, h0v[g]);
      h[g]  = hn;
      xb[g] = hn * wgc + xtr;

      float cc = row16_reduce(xb[g][0] * fw[0] + xb[g][1] * fw[1]);
      if ((tid & 15) == 15) part[g][t + 1][pgrp] = cc;

      #pragma unroll
      for (int k = 0; k < DEPTH - 1; ++k) xq[g][k] = xq[g][k + 1];
      xq[g][DEPTH - 1] = xC[g];
    }

    #pragma unroll
    for (int k = 0; k < DEPTH - 1; ++k){
      wxq[k] = wxq[k + 1]; wgq[k] = wgq[k + 1]; whq[k] = whq[k + 1];
      wuq[k] = wuq[k + 1]; mmq[k] = mmq[k + 1];
    }
    wxq[DEPTH - 1] = wxn; wgq[DEPTH - 1] = wgn; whq[DEPTH - 1] = whn;
    wuq[DEPTH - 1] = wun; mmq[DEPTH - 1] = mmn;
  }

  __syncthreads();

  // ---- epilogue: 128 threads = 2 batches x 64 l-rows, sum 16 row-partials
  if (tid < GB * LL){
    const int l  = tid & 63;
    const int g2 = tid >> 6;
    float s = 0.0f;
    #pragma unroll
    for (int j = 0; j < 16; ++j) s += part[g2][l][j];
    out[(size_t)l * BB + (b0 * GB + g2)] = fsigm(s + fcb[0]);
  }
}

extern "C" void kernel_launch(void* const* d_in, const int* in_sizes, int n_in,
                              void* d_out, int out_size, void* d_ws, size_t ws_size,
                              hipStream_t stream)
{
  const float* x   = (const float*)d_in[0];
  const float* wx  = (const float*)d_in[1];
  const float* wg  = (const float*)d_in[2];
  const float* wh  = (const float*)d_in[3];
  const float* wu  = (const float*)d_in[4];
  const float* m   = (const float*)d_in[5];
  const float* fcw = (const float*)d_in[6];
  const float* fcb = (const float*)d_in[7];
  float* out = (float*)d_out;
  rnn_fused_kernel<<<dim3(NBLK), dim3(NT), 0, stream>>>(x, wx, wg, wh, wu, m, fcw, fcb, out);
}

// Round 16
// 51.058 us; speedup vs baseline: 1.4807x; 1.2666x over previous
//
#include <hip/hip_runtime.h>

typedef float f4 __attribute__((ext_vector_type(4)));
typedef float f2 __attribute__((ext_vector_type(2)));

#define LL 64
#define BB 2048
#define DD 512
#define GB 2                 // batches per block (consecutive)
#define NBLK (BB / GB)       // 1024 blocks
#define DEPTH 3              // prefetch depth (VGPR-budgeted for 3 waves/SIMD)
#define LOG2E 1.442695040888963f

__device__ __forceinline__ float fexp2(float v){ return __builtin_amdgcn_exp2f(v); }
__device__ __forceinline__ float frcp_(float v){ return __builtin_amdgcn_rcpf(v); }
__device__ __forceinline__ float fsigm(float z){ return frcp_(1.0f + fexp2(-LOG2E*z)); }
__device__ __forceinline__ float ftanh_(float z){ return 1.0f - 2.0f*frcp_(1.0f + fexp2(2.0f*LOG2E*z)); }

__device__ __forceinline__ f4 ld4(const float* __restrict__ p){ return *(const f4*)p; }
__device__ __forceinline__ f4 vexp2(f4 v){ f4 r; r[0]=fexp2(v[0]); r[1]=fexp2(v[1]); r[2]=fexp2(v[2]); r[3]=fexp2(v[3]); return r; }
__device__ __forceinline__ f4 vrcp(f4 v){ f4 r; r[0]=frcp_(v[0]); r[1]=frcp_(v[1]); r[2]=frcp_(v[2]); r[3]=frcp_(v[3]); return r; }

// Quad reduction via DPP quad_perm adds: pure VALU, no DS pipe (R12: -8.4%)
__device__ __forceinline__ float quad_reduce_dpp(float v){
  int t1 = __builtin_amdgcn_update_dpp(0, __builtin_bit_cast(int, v),
                                       0xB1 /*quad_perm [1,0,3,2]*/, 0xF, 0xF, true);
  v += __builtin_bit_cast(float, t1);
  int t2 = __builtin_amdgcn_update_dpp(0, __builtin_bit_cast(int, v),
                                       0x4E /*quad_perm [2,3,0,1]*/, 0xF, 0xF, true);
  v += __builtin_bit_cast(float, t2);
  return v;
}

// (128,3): cap VGPR at ~170. DEPTH=3 footprint ~145 -> fits WITHOUT spill,
// giving 3 waves/SIMD (+50% TLP over R12's 2).
__global__ __launch_bounds__(128, 3) void rnn_fused_kernel(
    const float* __restrict__ x,
    const float* __restrict__ wxp, const float* __restrict__ wgp,
    const float* __restrict__ whp, const float* __restrict__ wup,
    const float* __restrict__ mp,  const float* __restrict__ fcw,
    const float* __restrict__ fcb, float* __restrict__ out)
{
  __shared__ float part[GB][LL][33];   // [g][l][quad-group], +1 pad
  const int tid = threadIdx.x;
  const int b0  = blockIdx.x;
  const int d0  = tid << 2;
  const int grp = tid >> 2;

  const f4 fw = ld4(fcw + d0);
  const f2 fwlo = __builtin_shufflevector(fw, fw, 0, 1);
  const f2 fwhi = __builtin_shufflevector(fw, fw, 2, 3);
  const size_t PL = (size_t)BB * DD;

  // consecutive batches: block handles b = b0*GB .. b0*GB+GB-1
  const float* xbase[GB];
  #pragma unroll
  for (int g = 0; g < GB; ++g)
    xbase[g] = x + (size_t)(b0 * GB + g) * DD + d0;

  // ---- deep prefetch rings: x[1..DEPTH] and weights[1..DEPTH]
  f4 xq[GB][DEPTH];
  f4 wxq[DEPTH], wgq[DEPTH], whq[DEPTH], wuq[DEPTH], mmq[DEPTH];
  #pragma unroll
  for (int k = 0; k < DEPTH; ++k){
    const int s = 1 + k;
    #pragma unroll
    for (int g = 0; g < GB; ++g)
      xq[g][k] = ld4(xbase[g] + (size_t)s * PL);
    wxq[k] = ld4(wxp + s * DD + d0);
    wgq[k] = ld4(wgp + s * DD + d0);
    whq[k] = ld4(whp + s * DD + d0);
    wuq[k] = ld4(wup + s * DD + d0);
    mmq[k] = ld4(mp  + s * DD + d0);
  }

  // ---- t = 0
  f4 w0x = ld4(wxp + d0);
  f4 w0g = ld4(wgp + d0);
  f4 h0v[GB], h[GB], xb[GB];
  #pragma unroll
  for (int g = 0; g < GB; ++g){
    f4 x0 = ld4(xbase[g]);
    float c0 = quad_reduce_dpp(x0[0]*fw[0] + x0[1]*fw[1] + x0[2]*fw[2] + x0[3]*fw[3]);
    if ((tid & 3) == 0) part[g][0][grp] = c0;

    float c1 = 0.0f;
    #pragma unroll
    for (int j = 0; j < 4; ++j){
      h0v[g][j] = ftanh_(x0[j] * w0x[j]);
      xb[g][j]  = h0v[g][j] * w0g[j] + x0[j];
      c1       += xb[g][j] * fw[j];
    }
    h[g] = h0v[g];
    c1 = quad_reduce_dpp(c1);
    if ((tid & 3) == 0) part[g][1][grp] = c1;
  }

  // ---- main scan: t = 1..62 (x[63]/w[63] never used); unroll 3 -> ring
  //      rotation becomes register renaming
  #pragma unroll 3
  for (int t = 1; t < LL - 1; ++t){
    const int tpn = (t + DEPTH <= LL - 2) ? (t + DEPTH) : (LL - 2);
    // issue ALL next-step loads first (consumed DEPTH iters from now)
    f4 xC[GB];
    #pragma unroll
    for (int g = 0; g < GB; ++g)
      xC[g] = ld4(xbase[g] + (size_t)tpn * PL);
    f4 wxn = ld4(wxp + tpn * DD + d0);
    f4 wgn = ld4(wgp + tpn * DD + d0);
    f4 whn = ld4(whp + tpn * DD + d0);
    f4 wun = ld4(wup + tpn * DD + d0);
    f4 mmn = ld4(mp  + tpn * DD + d0);

    // consume ring fronts (loaded DEPTH iters ago)
    f4 wxs = wxq[0] * (2.0f * LOG2E);
    f4 whs = whq[0] * (-LOG2E);
    f4 wus = wuq[0] * (-LOG2E);
    f4 wgc = wgq[0];
    f4 mmc = mmq[0];

    #pragma unroll
    for (int g = 0; g < GB; ++g){
      f4 xtr  = xb[g] + mmc * (xq[g][0] - xb[g]);
      f4 u    = 1.0f - 2.0f * vrcp(1.0f + vexp2(xtr * wxs));
      f4 sarg = h[g] * whs + u * wus;
      f4 ff   = vrcp(1.0f + vexp2(sarg)) * mmc;
      f4 mn   = __builtin_elementwise_min(1.0f - ff, u);
      f4 hn   = ff * h[g] + mn;
      hn      = __builtin_elementwise_max(hn, h0v[g]);
      h[g]  = hn;
      xb[g] = hn * wgc + xtr;

      f2 c2 = __builtin_shufflevector(xb[g], xb[g], 0, 1) * fwlo
            + __builtin_shufflevector(xb[g], xb[g], 2, 3) * fwhi;
      float cc = quad_reduce_dpp(c2[0] + c2[1]);
      if ((tid & 3) == 0) part[g][t + 1][grp] = cc;

      #pragma unroll
      for (int k = 0; k < DEPTH - 1; ++k) xq[g][k] = xq[g][k + 1];
      xq[g][DEPTH - 1] = xC[g];
    }

    #pragma unroll
    for (int k = 0; k < DEPTH - 1; ++k){
      wxq[k] = wxq[k + 1]; wgq[k] = wgq[k + 1]; whq[k] = whq[k + 1];
      wuq[k] = wuq[k + 1]; mmq[k] = mmq[k + 1];
    }
    wxq[DEPTH - 1] = wxn; wgq[DEPTH - 1] = wgn; whq[DEPTH - 1] = whn;
    wuq[DEPTH - 1] = wun; mmq[DEPTH - 1] = mmn;
  }

  __syncthreads();

  // ---- epilogue: 128 threads = 2 batches x 64 l-rows
  {
    const int l = tid & 63;
    const int g = tid >> 6;
    float s = 0.0f;
    #pragma unroll
    for (int j = 0; j < 32; ++j) s += part[g][l][j];
    out[(size_t)l * BB + (b0 * GB + g)] = fsigm(s + fcb[0]);
  }
}

extern "C" void kernel_launch(void* const* d_in, const int* in_sizes, int n_in,
                              void* d_out, int out_size, void* d_ws, size_t ws_size,
                              hipStream_t stream)
{
  const float* x   = (const float*)d_in[0];
  const float* wx  = (const float*)d_in[1];
  const float* wg  = (const float*)d_in[2];
  const float* wh  = (const float*)d_in[3];
  const float* wu  = (const float*)d_in[4];
  const float* m   = (const float*)d_in[5];
  const float* fcw = (const float*)d_in[6];
  const float* fcb = (const float*)d_in[7];
  float* out = (float*)d_out;
  rnn_fused_kernel<<<dim3(NBLK), dim3(128), 0, stream>>>(x, wx, wg, wh, wu, m, fcw, fcb, out);
}